// Round 8
// baseline (251.537 us; speedup 1.0000x reference)
//
#include <hip/hip_runtime.h>

// Problem constants (match reference)
#define N_PTS 1048576
#define C_PT 9
#define C_LB 20
#define V1 500000
#define V8 65536

// Bucketing: 256 bins per bucket (proven R2 geometry)
#define NB1 1954                 // ceil(V1/256)
#define NB8 256                  // V8/256
#define NBT (NB1 + NB8)          // 2210
#define KBLOCKS 256
#define PTS_PER_BLOCK (N_PTS / KBLOCKS)   // 4096
#define LB_STRIDE 21             // gcd(21,32)=1 -> spread LDS banks

// ---- bf16 helpers (manual RNE; inputs finite) ----
__device__ __forceinline__ unsigned f2bf(float f) {
    unsigned u = __float_as_uint(f);
    u += 0x7FFFu + ((u >> 16) & 1u);
    return u >> 16;
}
__device__ __forceinline__ float bf_lo(unsigned w) { return __uint_as_float(w << 16); }
__device__ __forceinline__ float bf_hi(unsigned w) { return __uint_as_float(w & 0xFFFF0000u); }

// K1: per-block LDS histogram over all 2210 buckets -> u16 matrix row.
__global__ __launch_bounds__(1024) void count_kernel(const int* __restrict__ inv1,
                                                     const int* __restrict__ inv8,
                                                     unsigned short* __restrict__ mat)
{
    __shared__ int hist[NBT];
    for (int k = threadIdx.x; k < NBT; k += 1024) hist[k] = 0;
    __syncthreads();
    int base_i = blockIdx.x * PTS_PER_BLOCK;
    for (int t = threadIdx.x; t < PTS_PER_BLOCK; t += 1024) {
        int i = base_i + t;
        atomicAdd(&hist[inv1[i] >> 8], 1);
        atomicAdd(&hist[NB1 + (inv8[i] >> 8)], 1);
    }
    __syncthreads();
    unsigned short* row = mat + (size_t)blockIdx.x * NBT;
    for (int k = threadIdx.x; k < NBT; k += 1024) row[k] = (unsigned short)hist[k];
}

// S1: per-bucket (column) exclusive scan over the 256 blocks, in place.
__global__ __launch_bounds__(256) void colscan_kernel(unsigned short* __restrict__ mat,
                                                      int* __restrict__ total)
{
    int wave = (int)((blockIdx.x * 256 + threadIdx.x) >> 6);
    int lane = threadIdx.x & 63;
    if (wave >= NBT) return;
    int carry = 0;
    for (int c = 0; c < KBLOCKS; c += 64) {
        int b = c + lane;
        int v = (int)mat[(size_t)b * NBT + wave];
        int s = v;
        #pragma unroll
        for (int d = 1; d < 64; d <<= 1) {
            int u = __shfl_up(s, d, 64);
            if (lane >= d) s += u;
        }
        mat[(size_t)b * NBT + wave] = (unsigned short)(s - v + carry);
        carry += __shfl(s, 63, 64);
    }
    if (lane == 0) total[wave] = carry;
}

// S2: exclusive scan of bucket totals -> base (separate per scale).
__global__ __launch_bounds__(64) void basescan_kernel(const int* __restrict__ total,
                                                      int* __restrict__ base)
{
    int lane = threadIdx.x;
    int carry = 0;
    for (int c = 0; c < NB1; c += 64) {
        int k = c + lane;
        int v = (k < NB1) ? total[k] : 0;
        int s = v;
        #pragma unroll
        for (int d = 1; d < 64; d <<= 1) {
            int u = __shfl_up(s, d, 64);
            if (lane >= d) s += u;
        }
        if (k < NB1) base[k] = s - v + carry;
        carry += __shfl(s, 63, 64);
    }
    carry = 0;
    for (int c = 0; c < NB8; c += 64) {
        int k = c + lane;
        int v = total[NB1 + k];
        int s = v;
        #pragma unroll
        for (int d = 1; d < 64; d <<= 1) {
            int u = __shfl_up(s, d, 64);
            if (lane >= d) s += u;
        }
        base[NB1 + k] = s - v + carry;
        carry += __shfl(s, 63, 64);
    }
}

// K2: PAYLOAD scatter. Streaming-read points/labels/indices; write bf16
// payload rows at the sorted destination. Writes are fire-and-forget
// (no latency round trip) and land in L2-resident bucket regions:
// labels bucket ~ 4096*40B = 160KB, points bucket ~ 537*20B = 11KB.
// This removes the random-GATHER that pinned R2/R4/R5/R6 at ~170us.
__global__ __launch_bounds__(1024) void scatter_pay_kernel(const float* __restrict__ points,
                                                           const float* __restrict__ labels,
                                                           const int* __restrict__ inv1,
                                                           const int* __restrict__ inv8,
                                                           const unsigned short* __restrict__ mat,
                                                           const int* __restrict__ base,
                                                           unsigned* __restrict__ lblPay, // [N*10] u32 (40B rows)
                                                           unsigned* __restrict__ ptsPay, // [N*5]  u32 (20B rows)
                                                           unsigned char* __restrict__ bins8) // [N]
{
    __shared__ int off[NBT];
    __shared__ int cnt[NBT];
    const unsigned short* row = mat + (size_t)blockIdx.x * NBT;
    for (int k = threadIdx.x; k < NBT; k += 1024) {
        off[k] = base[k] + (int)row[k];
        cnt[k] = 0;
    }
    __syncthreads();
    int base_i = blockIdx.x * PTS_PER_BLOCK;
    for (int t = threadIdx.x; t < PTS_PER_BLOCK; t += 1024) {
        int i = base_i + t;

        // ---- points -> ptsPay[dest1], bin packed in dword4 high half ----
        int v1 = inv1[i];
        int k1 = v1 >> 8;
        int r1 = atomicAdd(&cnt[k1], 1);
        int dest1 = off[k1] + r1;
        const float* __restrict__ p = points + (size_t)i * C_PT;
        unsigned* __restrict__ pd = ptsPay + (size_t)dest1 * 5;
        pd[0] = f2bf(p[0]) | (f2bf(p[1]) << 16);
        pd[1] = f2bf(p[2]) | (f2bf(p[3]) << 16);
        pd[2] = f2bf(p[4]) | (f2bf(p[5]) << 16);
        pd[3] = f2bf(p[6]) | (f2bf(p[7]) << 16);
        pd[4] = f2bf(p[8]) | ((unsigned)(v1 & 255) << 16);

        // ---- labels -> lblPay[dest8] (5 x uint2), bin byte separate ----
        int v8 = inv8[i];
        int k8 = NB1 + (v8 >> 8);
        int r8 = atomicAdd(&cnt[k8], 1);
        int dest8 = off[k8] + r8;
        const float4* __restrict__ l4 = reinterpret_cast<const float4*>(labels) + (size_t)i * 5;
        uint2* __restrict__ ld = reinterpret_cast<uint2*>(lblPay + (size_t)dest8 * 10);
        #pragma unroll
        for (int q = 0; q < 5; ++q) {
            float4 v = l4[q];
            ld[q] = make_uint2(f2bf(v.x) | (f2bf(v.y) << 16),
                               f2bf(v.z) | (f2bf(v.w) << 16));
        }
        bins8[dest8] = (unsigned char)(v8 & 255);
    }
}

// K3: FUSED accumulation from SEQUENTIAL payload streams.
// Blocks [0, NB8): label buckets; blocks [NB8, NB8+NB1): point buckets.
__global__ __launch_bounds__(512) void accum_fused_kernel(const unsigned* __restrict__ lblPay,
                                                          const unsigned* __restrict__ ptsPay,
                                                          const unsigned char* __restrict__ bins8,
                                                          const int* __restrict__ base,
                                                          const int* __restrict__ total,
                                                          float* __restrict__ feat_out,
                                                          float* __restrict__ lbl_out)
{
    __shared__ float acc[256 * LB_STRIDE];
    __shared__ int cnt[256];
    if (blockIdx.x < NB8) {
        int b = blockIdx.x;
        for (int j = threadIdx.x; j < 256 * LB_STRIDE; j += 512) acc[j] = 0.0f;
        for (int j = threadIdx.x; j < 256; j += 512) cnt[j] = 0;
        __syncthreads();
        int start = base[NB1 + b];
        int num   = total[NB1 + b];
        for (int t = threadIdx.x; t < num; t += 512) {
            int bin = (int)bins8[start + t];
            const uint2* __restrict__ r = reinterpret_cast<const uint2*>(lblPay + (size_t)(start + t) * 10);
            float* a = acc + bin * LB_STRIDE;
            #pragma unroll
            for (int q = 0; q < 5; ++q) {
                uint2 w = r[q];
                atomicAdd(&a[4 * q + 0], bf_lo(w.x));
                atomicAdd(&a[4 * q + 1], bf_hi(w.x));
                atomicAdd(&a[4 * q + 2], bf_lo(w.y));
                atomicAdd(&a[4 * q + 3], bf_hi(w.y));
            }
            atomicAdd(&cnt[bin], 1);
        }
        __syncthreads();
        size_t obase = (size_t)b * 256 * C_LB;
        for (int j = threadIdx.x; j < 256 * C_LB; j += 512) {
            int bin = j / C_LB, c = j - bin * C_LB;
            int n = cnt[bin];
            float d = (float)(n > 0 ? n : 1);
            lbl_out[obase + j] = acc[bin * LB_STRIDE + c] / d;
        }
    } else {
        int b = blockIdx.x - NB8;
        for (int j = threadIdx.x; j < 256 * C_PT; j += 512) acc[j] = 0.0f;
        for (int j = threadIdx.x; j < 256; j += 512) cnt[j] = 0;
        __syncthreads();
        int start = base[b];
        int num   = total[b];
        for (int t = threadIdx.x; t < num; t += 512) {
            const unsigned* __restrict__ r = ptsPay + (size_t)(start + t) * 5;
            unsigned w0 = r[0], w1 = r[1], w2 = r[2], w3 = r[3], w4 = r[4];
            int bin = (int)(w4 >> 16);
            float* a = acc + bin * C_PT;
            atomicAdd(&a[0], bf_lo(w0)); atomicAdd(&a[1], bf_hi(w0));
            atomicAdd(&a[2], bf_lo(w1)); atomicAdd(&a[3], bf_hi(w1));
            atomicAdd(&a[4], bf_lo(w2)); atomicAdd(&a[5], bf_hi(w2));
            atomicAdd(&a[6], bf_lo(w3)); atomicAdd(&a[7], bf_hi(w3));
            atomicAdd(&a[8], bf_lo(w4));
            atomicAdd(&cnt[bin], 1);
        }
        __syncthreads();
        int vbase = b * 256;
        int nbins = min(256, V1 - vbase);
        for (int j = threadIdx.x; j < nbins * C_PT; j += 512) {
            int bin = j / C_PT, c = j - bin * C_PT;
            int n = cnt[bin];
            float d = (float)(n > 0 ? n : 1);
            feat_out[(size_t)(vbase + bin) * C_PT + c] = acc[bin * C_PT + c] / d;
        }
    }
}

// ---------------- Fallback A: R6-proven id-sort + register-batch gather ----
__global__ __launch_bounds__(1024) void scatter_kernel(const int* __restrict__ inv1,
                                                       const int* __restrict__ inv8,
                                                       const unsigned short* __restrict__ mat,
                                                       const int* __restrict__ base,
                                                       int* __restrict__ sorted1,
                                                       int* __restrict__ sorted8)
{
    __shared__ int off[NBT];
    __shared__ int cnt[NBT];
    const unsigned short* row = mat + (size_t)blockIdx.x * NBT;
    for (int k = threadIdx.x; k < NBT; k += 1024) {
        off[k] = base[k] + (int)row[k];
        cnt[k] = 0;
    }
    __syncthreads();
    int base_i = blockIdx.x * PTS_PER_BLOCK;
    for (int t = threadIdx.x; t < PTS_PER_BLOCK; t += 1024) {
        int i = base_i + t;
        int v1 = inv1[i];
        int k1 = v1 >> 8;
        int r1 = atomicAdd(&cnt[k1], 1);
        sorted1[off[k1] + r1] = i | ((v1 & 255) << 20);
        int v8 = inv8[i];
        int k8 = NB1 + (v8 >> 8);
        int r8 = atomicAdd(&cnt[k8], 1);
        sorted8[off[k8] + r8] = i | ((v8 & 255) << 20);
    }
}

__global__ __launch_bounds__(1024) void accum8_raw_kernel(const float* __restrict__ labels,
                                                          const int* __restrict__ sorted8,
                                                          const int* __restrict__ base,
                                                          const int* __restrict__ total,
                                                          float* __restrict__ lbl_out)
{
    __shared__ float acc[256 * LB_STRIDE];
    __shared__ int cnt[256];
    for (int j = threadIdx.x; j < 256 * LB_STRIDE; j += 1024) acc[j] = 0.0f;
    if (threadIdx.x < 256) cnt[threadIdx.x] = 0;
    __syncthreads();
    int b = blockIdx.x;
    int start = base[NB1 + b];
    int num   = total[NB1 + b];
    int q = threadIdx.x & 3;
    for (int t = (int)(threadIdx.x >> 2); t < num; t += 256) {
        int packed = sorted8[start + t];
        int idx = packed & 0xFFFFF;
        int bin = packed >> 20;
        const float4* __restrict__ r4 = reinterpret_cast<const float4*>(labels) + (size_t)idx * 5;
        float4 v = r4[q];
        float* a = acc + bin * LB_STRIDE;
        atomicAdd(&a[q * 4 + 0], v.x);
        atomicAdd(&a[q * 4 + 1], v.y);
        atomicAdd(&a[q * 4 + 2], v.z);
        atomicAdd(&a[q * 4 + 3], v.w);
        if (q == 0) {
            float4 w = r4[4];
            atomicAdd(&a[16], w.x); atomicAdd(&a[17], w.y);
            atomicAdd(&a[18], w.z); atomicAdd(&a[19], w.w);
            atomicAdd(&cnt[bin], 1);
        }
    }
    __syncthreads();
    size_t obase = (size_t)b * 256 * C_LB;
    for (int j = threadIdx.x; j < 256 * C_LB; j += 1024) {
        int bin = j / C_LB, c = j - bin * C_LB;
        int n = cnt[bin];
        float d = (float)(n > 0 ? n : 1);
        lbl_out[obase + j] = acc[bin * LB_STRIDE + c] / d;
    }
}

__global__ __launch_bounds__(256) void accum1_raw_kernel(const float* __restrict__ points,
                                                         const int* __restrict__ sorted1,
                                                         const int* __restrict__ base,
                                                         const int* __restrict__ total,
                                                         float* __restrict__ feat_out)
{
    __shared__ float acc[256 * C_PT];
    __shared__ int cnt[256];
    for (int j = threadIdx.x; j < 256 * C_PT; j += 256) acc[j] = 0.0f;
    cnt[threadIdx.x] = 0;
    __syncthreads();
    int b = blockIdx.x;
    int start = base[b];
    int num   = total[b];
    int q = threadIdx.x & 3;
    for (int t = (int)(threadIdx.x >> 2); t < num; t += 64) {
        int packed = sorted1[start + t];
        int idx = packed & 0xFFFFF;
        int bin = packed >> 20;
        const float* __restrict__ row = points + (size_t)idx * C_PT;
        float* a = acc + bin * C_PT;
        atomicAdd(&a[q],     row[q]);
        atomicAdd(&a[q + 4], row[q + 4]);
        if (q == 0) {
            atomicAdd(&a[8], row[8]);
            atomicAdd(&cnt[bin], 1);
        }
    }
    __syncthreads();
    int vbase = b * 256;
    int nbins = min(256, V1 - vbase);
    for (int j = threadIdx.x; j < nbins * C_PT; j += 256) {
        int bin = j / C_PT, c = j - bin * C_PT;
        int n = cnt[bin];
        float d = (float)(n > 0 ? n : 1);
        feat_out[(size_t)(vbase + bin) * C_PT + c] = acc[bin * C_PT + c] / d;
    }
}

// ---------------- Fallback B: R0 atomic scatter ----------------------------
__global__ void voxel_scatter_add_kernel(const float* __restrict__ points,
                                         const int* __restrict__ inv1,
                                         const float* __restrict__ labels,
                                         const int* __restrict__ inv8,
                                         float* feat_sum, float* lbl_sum,
                                         float* cnt1, float* cnt8)
{
    int i = blockIdx.x * blockDim.x + threadIdx.x;
    if (i >= N_PTS) return;
    int v1 = inv1[i];
    int v8 = inv8[i];
    const float* p = points + (size_t)i * C_PT;
    float* f = feat_sum + (size_t)v1 * C_PT;
#pragma unroll
    for (int c = 0; c < C_PT; ++c) atomicAdd(&f[c], p[c]);
    atomicAdd(&cnt1[v1], 1.0f);
    const float* l = labels + (size_t)i * C_LB;
    float* o = lbl_sum + (size_t)v8 * C_LB;
#pragma unroll
    for (int c = 0; c < C_LB; ++c) atomicAdd(&o[c], l[c]);
    atomicAdd(&cnt8[v8], 1.0f);
}

__global__ void voxel_divide_kernel(float* out, const float* cnt1, const float* cnt8)
{
    const int totaln = V1 * C_PT + V8 * C_LB;
    for (int i = blockIdx.x * blockDim.x + threadIdx.x; i < totaln;
         i += gridDim.x * blockDim.x) {
        float c = (i < V1 * C_PT) ? cnt1[i / C_PT] : cnt8[(i - V1 * C_PT) / C_LB];
        out[i] /= fmaxf(c, 1.0f);
    }
}

extern "C" void kernel_launch(void* const* d_in, const int* in_sizes, int n_in,
                              void* d_out, int out_size, void* d_ws, size_t ws_size,
                              hipStream_t stream) {
    const float* points = (const float*)d_in[0];
    const int*   inv1   = (const int*)d_in[1];
    const float* labels = (const float*)d_in[2];
    const int*   inv8   = (const int*)d_in[3];

    float* out      = (float*)d_out;
    float* feat_out = out;                       // [V1, C_PT]
    float* lbl_out  = out + (size_t)V1 * C_PT;   // [V8, C_LB]

    // Primary layout: lblPay u32[N*10] | ptsPay u32[N*5] | bins8 u8[N] |
    //                 total[NBT] | base[NBT] | mat u16[256][NBT]  (~62.1 MB)
    const size_t pay_need = (size_t)N_PTS * 10 * 4 + (size_t)N_PTS * 5 * 4 + (size_t)N_PTS
                          + (size_t)2 * NBT * sizeof(int)
                          + (size_t)KBLOCKS * NBT * sizeof(unsigned short);
    // Fallback A layout (R6): sorted1[N] | sorted8[N] | total | base | mat (~9.45 MB)
    const size_t idx_need = ((size_t)2 * N_PTS + 2 * NBT) * sizeof(int)
                          + (size_t)KBLOCKS * NBT * sizeof(unsigned short);
    const int block = 256;

    if (ws_size >= pay_need) {
        unsigned* lblPay = (unsigned*)d_ws;
        unsigned* ptsPay = lblPay + (size_t)N_PTS * 10;
        unsigned char* bins8 = (unsigned char*)(ptsPay + (size_t)N_PTS * 5);
        int* total = (int*)(bins8 + N_PTS);
        int* basep = total + NBT;
        unsigned short* mat = (unsigned short*)(basep + NBT);

        count_kernel<<<KBLOCKS, 1024, 0, stream>>>(inv1, inv8, mat);
        colscan_kernel<<<(NBT + 3) / 4, 256, 0, stream>>>(mat, total);
        basescan_kernel<<<1, 64, 0, stream>>>(total, basep);
        scatter_pay_kernel<<<KBLOCKS, 1024, 0, stream>>>(points, labels, inv1, inv8,
                                                         mat, basep, lblPay, ptsPay,
                                                         bins8);
        accum_fused_kernel<<<NB8 + NB1, 512, 0, stream>>>(lblPay, ptsPay, bins8,
                                                          basep, total,
                                                          feat_out, lbl_out);
    } else if (ws_size >= idx_need) {
        int* sorted1 = (int*)d_ws;
        int* sorted8 = sorted1 + N_PTS;
        int* total   = sorted8 + N_PTS;
        int* basep   = total + NBT;
        unsigned short* mat = (unsigned short*)(basep + NBT);

        count_kernel<<<KBLOCKS, 1024, 0, stream>>>(inv1, inv8, mat);
        colscan_kernel<<<(NBT + 3) / 4, 256, 0, stream>>>(mat, total);
        basescan_kernel<<<1, 64, 0, stream>>>(total, basep);
        scatter_kernel<<<KBLOCKS, 1024, 0, stream>>>(inv1, inv8, mat, basep,
                                                     sorted1, sorted8);
        accum8_raw_kernel<<<NB8, 1024, 0, stream>>>(labels, sorted8, basep, total,
                                                    lbl_out);
        accum1_raw_kernel<<<NB1, 256, 0, stream>>>(points, sorted1, basep, total,
                                                   feat_out);
    } else {
        float* cnt1 = (float*)d_ws;
        float* cnt8 = cnt1 + V1;
        hipMemsetAsync(d_out, 0, (size_t)out_size * sizeof(float), stream);
        hipMemsetAsync(d_ws, 0, ((size_t)V1 + V8) * sizeof(float), stream);
        voxel_scatter_add_kernel<<<(N_PTS + block - 1) / block, block, 0, stream>>>(
            points, inv1, labels, inv8, feat_out, lbl_out, cnt1, cnt8);
        voxel_divide_kernel<<<2048, block, 0, stream>>>(out, cnt1, cnt8);
    }
}

// Round 9
// 117.744 us; speedup vs baseline: 2.1363x; 2.1363x over previous
//
#include <hip/hip_runtime.h>

// Problem constants (match reference)
#define N_PTS 1048576
#define C_PT 9
#define C_LB 20
#define V1 500000
#define V8 65536

// Bucketing: 256 bins per bucket (proven R2 geometry)
#define NB1 1954                 // ceil(V1/256)
#define NB8 256                  // V8/256
#define NBT (NB1 + NB8)          // 2210
#define KBLOCKS 256
#define PTS_PER_BLOCK (N_PTS / KBLOCKS)   // 4096
#define CAP 4096                 // counting-sort chunk capacity per block

// K1: per-block LDS histogram over all 2210 buckets -> u16 matrix row.
// (2M LDS int atomics total — ~11us at the measured 186 G/s atomic wall.)
__global__ __launch_bounds__(1024) void count_kernel(const int* __restrict__ inv1,
                                                     const int* __restrict__ inv8,
                                                     unsigned short* __restrict__ mat)
{
    __shared__ int hist[NBT];
    for (int k = threadIdx.x; k < NBT; k += 1024) hist[k] = 0;
    __syncthreads();
    int base_i = blockIdx.x * PTS_PER_BLOCK;
    for (int t = threadIdx.x; t < PTS_PER_BLOCK; t += 1024) {
        int i = base_i + t;
        atomicAdd(&hist[inv1[i] >> 8], 1);
        atomicAdd(&hist[NB1 + (inv8[i] >> 8)], 1);
    }
    __syncthreads();
    unsigned short* row = mat + (size_t)blockIdx.x * NBT;
    for (int k = threadIdx.x; k < NBT; k += 1024) row[k] = (unsigned short)hist[k];
}

// S1: per-bucket (column) exclusive scan over the 256 blocks, in place.
__global__ __launch_bounds__(256) void colscan_kernel(unsigned short* __restrict__ mat,
                                                      int* __restrict__ total)
{
    int wave = (int)((blockIdx.x * 256 + threadIdx.x) >> 6);
    int lane = threadIdx.x & 63;
    if (wave >= NBT) return;
    int carry = 0;
    for (int c = 0; c < KBLOCKS; c += 64) {
        int b = c + lane;
        int v = (int)mat[(size_t)b * NBT + wave];
        int s = v;
        #pragma unroll
        for (int d = 1; d < 64; d <<= 1) {
            int u = __shfl_up(s, d, 64);
            if (lane >= d) s += u;
        }
        mat[(size_t)b * NBT + wave] = (unsigned short)(s - v + carry);
        carry += __shfl(s, 63, 64);
    }
    if (lane == 0) total[wave] = carry;
}

// S2: exclusive scan of bucket totals -> base (separate per scale).
__global__ __launch_bounds__(64) void basescan_kernel(const int* __restrict__ total,
                                                      int* __restrict__ base)
{
    int lane = threadIdx.x;
    int carry = 0;
    for (int c = 0; c < NB1; c += 64) {
        int k = c + lane;
        int v = (k < NB1) ? total[k] : 0;
        int s = v;
        #pragma unroll
        for (int d = 1; d < 64; d <<= 1) {
            int u = __shfl_up(s, d, 64);
            if (lane >= d) s += u;
        }
        if (k < NB1) base[k] = s - v + carry;
        carry += __shfl(s, 63, 64);
    }
    carry = 0;
    for (int c = 0; c < NB8; c += 64) {
        int k = c + lane;
        int v = total[NB1 + k];
        int s = v;
        #pragma unroll
        for (int d = 1; d < 64; d <<= 1) {
            int u = __shfl_up(s, d, 64);
            if (lane >= d) s += u;
        }
        base[NB1 + k] = s - v + carry;
        carry += __shfl(s, 63, 64);
    }
}

// K2: place each point id (packed with 8-bit in-bucket bin) into sorted arrays.
__global__ __launch_bounds__(1024) void scatter_kernel(const int* __restrict__ inv1,
                                                       const int* __restrict__ inv8,
                                                       const unsigned short* __restrict__ mat,
                                                       const int* __restrict__ base,
                                                       int* __restrict__ sorted1,
                                                       int* __restrict__ sorted8)
{
    __shared__ int off[NBT];
    __shared__ int cnt[NBT];
    const unsigned short* row = mat + (size_t)blockIdx.x * NBT;
    for (int k = threadIdx.x; k < NBT; k += 1024) {
        off[k] = base[k] + (int)row[k];
        cnt[k] = 0;
    }
    __syncthreads();
    int base_i = blockIdx.x * PTS_PER_BLOCK;
    for (int t = threadIdx.x; t < PTS_PER_BLOCK; t += 1024) {
        int i = base_i + t;
        int v1 = inv1[i];
        int k1 = v1 >> 8;
        int r1 = atomicAdd(&cnt[k1], 1);
        sorted1[off[k1] + r1] = i | ((v1 & 255) << 20);
        int v8 = inv8[i];
        int k8 = NB1 + (v8 >> 8);
        int r8 = atomicAdd(&cnt[k8], 1);
        sorted8[off[k8] + r8] = i | ((v8 & 255) << 20);
    }
}

// K3: accumulation WITHOUT per-channel LDS atomics (the ~186 G lane-atomic/s
// wall that pinned R2/R5/R6/R7 at ~167us for 31M atomics).
// Per bucket: in-LDS counting sort of row indices by bin (2 LDS atomics/row),
// then thread v register-accumulates its voxel's contiguous row list with
// plain f32 gathers (no atomics, 64 independent chains per wave), divides,
// writes output exactly once.
__global__ __launch_bounds__(256) void accum_voxel_kernel(const float* __restrict__ points,
                                                          const float* __restrict__ labels,
                                                          const int* __restrict__ sorted1,
                                                          const int* __restrict__ sorted8,
                                                          const int* __restrict__ base,
                                                          const int* __restrict__ total,
                                                          float* __restrict__ feat_out,
                                                          float* __restrict__ lbl_out)
{
    __shared__ unsigned stage[CAP];        // sorted words of current chunk (16KB)
    __shared__ unsigned short perm[CAP];   // bin-sorted row order (8KB)
    __shared__ int hist[256];
    __shared__ int starts[256];
    __shared__ int cursor[256];
    __shared__ int wsum[4];

    const int tid  = threadIdx.x;
    const int lane = tid & 63;
    const int wid  = tid >> 6;

    if (blockIdx.x < NB8) {
        // ---------------- labels bucket ----------------
        int b = blockIdx.x;
        int start = base[NB1 + b];
        int num   = total[NB1 + b];
        float acc[C_LB];
        #pragma unroll
        for (int c = 0; c < C_LB; ++c) acc[c] = 0.0f;
        int mycnt = 0;

        for (int cbase = 0; cbase < num; cbase += CAP) {
            int csize = min(CAP, num - cbase);
            __syncthreads();                       // protect stage/perm reuse
            for (int t = tid; t < csize; t += 256)
                stage[t] = (unsigned)sorted8[start + cbase + t];
            hist[tid] = 0;
            __syncthreads();
            for (int t = tid; t < csize; t += 256)
                atomicAdd(&hist[stage[t] >> 20], 1);
            __syncthreads();
            // exclusive scan of hist (4-wave shfl scan + cross-wave offsets)
            int x = hist[tid];
            int s = x;
            #pragma unroll
            for (int d = 1; d < 64; d <<= 1) {
                int u = __shfl_up(s, d, 64);
                if (lane >= d) s += u;
            }
            if (lane == 63) wsum[wid] = s;
            __syncthreads();
            int off = 0;
            #pragma unroll
            for (int w = 0; w < 4; ++w) if (w < wid) off += wsum[w];
            starts[tid] = off + s - x;
            cursor[tid] = 0;
            __syncthreads();
            // rank: place row index into per-bin contiguous region
            for (int t = tid; t < csize; t += 256) {
                int bin = (int)(stage[t] >> 20);
                int r = atomicAdd(&cursor[bin], 1);
                perm[starts[bin] + r] = (unsigned short)t;
            }
            __syncthreads();
            // gather: thread tid owns voxel (b*256 + tid)
            int n  = hist[tid];
            int s0 = starts[tid];
            for (int j = 0; j < n; ++j) {
                int t = (int)perm[s0 + j];
                unsigned idx = stage[t] & 0xFFFFFu;
                const float4* __restrict__ r4 =
                    reinterpret_cast<const float4*>(labels) + (size_t)idx * 5;
                float4 v0 = r4[0], v1 = r4[1], v2 = r4[2], v3 = r4[3], v4 = r4[4];
                acc[0]  += v0.x; acc[1]  += v0.y; acc[2]  += v0.z; acc[3]  += v0.w;
                acc[4]  += v1.x; acc[5]  += v1.y; acc[6]  += v1.z; acc[7]  += v1.w;
                acc[8]  += v2.x; acc[9]  += v2.y; acc[10] += v2.z; acc[11] += v2.w;
                acc[12] += v3.x; acc[13] += v3.y; acc[14] += v3.z; acc[15] += v3.w;
                acc[16] += v4.x; acc[17] += v4.y; acc[18] += v4.z; acc[19] += v4.w;
            }
            mycnt += n;
        }
        float inv = 1.0f / (float)(mycnt > 0 ? mycnt : 1);
        // lbl_out base offset = V1*C_PT floats = 18MB (16B aligned); 80B rows.
        float4* orow = reinterpret_cast<float4*>(lbl_out + ((size_t)b * 256 + tid) * C_LB);
        orow[0] = make_float4(acc[0] * inv,  acc[1] * inv,  acc[2] * inv,  acc[3] * inv);
        orow[1] = make_float4(acc[4] * inv,  acc[5] * inv,  acc[6] * inv,  acc[7] * inv);
        orow[2] = make_float4(acc[8] * inv,  acc[9] * inv,  acc[10] * inv, acc[11] * inv);
        orow[3] = make_float4(acc[12] * inv, acc[13] * inv, acc[14] * inv, acc[15] * inv);
        orow[4] = make_float4(acc[16] * inv, acc[17] * inv, acc[18] * inv, acc[19] * inv);
    } else {
        // ---------------- points bucket ----------------
        int b = blockIdx.x - NB8;
        int start = base[b];
        int num   = total[b];
        float acc[C_PT];
        #pragma unroll
        for (int c = 0; c < C_PT; ++c) acc[c] = 0.0f;
        int mycnt = 0;

        for (int cbase = 0; cbase < num; cbase += CAP) {
            int csize = min(CAP, num - cbase);
            __syncthreads();
            for (int t = tid; t < csize; t += 256)
                stage[t] = (unsigned)sorted1[start + cbase + t];
            hist[tid] = 0;
            __syncthreads();
            for (int t = tid; t < csize; t += 256)
                atomicAdd(&hist[stage[t] >> 20], 1);
            __syncthreads();
            int x = hist[tid];
            int s = x;
            #pragma unroll
            for (int d = 1; d < 64; d <<= 1) {
                int u = __shfl_up(s, d, 64);
                if (lane >= d) s += u;
            }
            if (lane == 63) wsum[wid] = s;
            __syncthreads();
            int off = 0;
            #pragma unroll
            for (int w = 0; w < 4; ++w) if (w < wid) off += wsum[w];
            starts[tid] = off + s - x;
            cursor[tid] = 0;
            __syncthreads();
            for (int t = tid; t < csize; t += 256) {
                int bin = (int)(stage[t] >> 20);
                int r = atomicAdd(&cursor[bin], 1);
                perm[starts[bin] + r] = (unsigned short)t;
            }
            __syncthreads();
            int n  = hist[tid];
            int s0 = starts[tid];
            for (int j = 0; j < n; ++j) {
                int t = (int)perm[s0 + j];
                unsigned idx = stage[t] & 0xFFFFFu;
                const float* __restrict__ r = points + (size_t)idx * C_PT;
                float p0 = r[0], p1 = r[1], p2 = r[2], p3 = r[3], p4 = r[4];
                float p5 = r[5], p6 = r[6], p7 = r[7], p8 = r[8];
                acc[0] += p0; acc[1] += p1; acc[2] += p2; acc[3] += p3;
                acc[4] += p4; acc[5] += p5; acc[6] += p6; acc[7] += p7;
                acc[8] += p8;
            }
            mycnt += n;
        }
        int v = b * 256 + tid;
        if (v < V1) {
            float inv = 1.0f / (float)(mycnt > 0 ? mycnt : 1);
            float* __restrict__ orow = feat_out + (size_t)v * C_PT;
            #pragma unroll
            for (int c = 0; c < C_PT; ++c) orow[c] = acc[c] * inv;
        }
    }
}

// ---------------- Fallback: R0 atomic scatter (ws tiny) --------------------
__global__ void voxel_scatter_add_kernel(const float* __restrict__ points,
                                         const int* __restrict__ inv1,
                                         const float* __restrict__ labels,
                                         const int* __restrict__ inv8,
                                         float* feat_sum, float* lbl_sum,
                                         float* cnt1, float* cnt8)
{
    int i = blockIdx.x * blockDim.x + threadIdx.x;
    if (i >= N_PTS) return;
    int v1 = inv1[i];
    int v8 = inv8[i];
    const float* p = points + (size_t)i * C_PT;
    float* f = feat_sum + (size_t)v1 * C_PT;
#pragma unroll
    for (int c = 0; c < C_PT; ++c) atomicAdd(&f[c], p[c]);
    atomicAdd(&cnt1[v1], 1.0f);
    const float* l = labels + (size_t)i * C_LB;
    float* o = lbl_sum + (size_t)v8 * C_LB;
#pragma unroll
    for (int c = 0; c < C_LB; ++c) atomicAdd(&o[c], l[c]);
    atomicAdd(&cnt8[v8], 1.0f);
}

__global__ void voxel_divide_kernel(float* out, const float* cnt1, const float* cnt8)
{
    const int totaln = V1 * C_PT + V8 * C_LB;
    for (int i = blockIdx.x * blockDim.x + threadIdx.x; i < totaln;
         i += gridDim.x * blockDim.x) {
        float c = (i < V1 * C_PT) ? cnt1[i / C_PT] : cnt8[(i - V1 * C_PT) / C_LB];
        out[i] /= fmaxf(c, 1.0f);
    }
}

extern "C" void kernel_launch(void* const* d_in, const int* in_sizes, int n_in,
                              void* d_out, int out_size, void* d_ws, size_t ws_size,
                              hipStream_t stream) {
    const float* points = (const float*)d_in[0];
    const int*   inv1   = (const int*)d_in[1];
    const float* labels = (const float*)d_in[2];
    const int*   inv8   = (const int*)d_in[3];

    float* out      = (float*)d_out;
    float* feat_out = out;                       // [V1, C_PT]
    float* lbl_out  = out + (size_t)V1 * C_PT;   // [V8, C_LB]

    // ws layout (EXACT R2, proven): sorted1[N] | sorted8[N] | total[NBT] |
    //                               base[NBT] | mat u16[256][NBT]   (~9.45 MB)
    const size_t need = ((size_t)2 * N_PTS + 2 * NBT) * sizeof(int)
                      + (size_t)KBLOCKS * NBT * sizeof(unsigned short);
    if (ws_size >= need) {
        int* sorted1 = (int*)d_ws;
        int* sorted8 = sorted1 + N_PTS;
        int* total   = sorted8 + N_PTS;
        int* basep   = total + NBT;
        unsigned short* mat = (unsigned short*)(basep + NBT);

        count_kernel<<<KBLOCKS, 1024, 0, stream>>>(inv1, inv8, mat);
        colscan_kernel<<<(NBT + 3) / 4, 256, 0, stream>>>(mat, total);
        basescan_kernel<<<1, 64, 0, stream>>>(total, basep);
        scatter_kernel<<<KBLOCKS, 1024, 0, stream>>>(inv1, inv8, mat, basep,
                                                     sorted1, sorted8);
        accum_voxel_kernel<<<NB8 + NB1, 256, 0, stream>>>(points, labels, sorted1,
                                                          sorted8, basep, total,
                                                          feat_out, lbl_out);
    } else {
        // Fallback: naive atomic scatter (correct, slower).
        float* cnt1 = (float*)d_ws;
        float* cnt8 = cnt1 + V1;
        hipMemsetAsync(d_out, 0, (size_t)out_size * sizeof(float), stream);
        hipMemsetAsync(d_ws, 0, ((size_t)V1 + V8) * sizeof(float), stream);
        const int block = 256;
        voxel_scatter_add_kernel<<<(N_PTS + block - 1) / block, block, 0, stream>>>(
            points, inv1, labels, inv8, feat_out, lbl_out, cnt1, cnt8);
        voxel_divide_kernel<<<2048, block, 0, stream>>>(out, cnt1, cnt8);
    }
}

// Round 10
// 109.480 us; speedup vs baseline: 2.2976x; 1.0755x over previous
//
#include <hip/hip_runtime.h>

// Problem constants (match reference)
#define N_PTS 1048576
#define C_PT 9
#define C_LB 20
#define V1 500000
#define V8 65536

// Bucketing: 256 bins per bucket (proven R2 geometry)
#define NB1 1954                 // ceil(V1/256)
#define NB8 256                  // V8/256
#define NBT (NB1 + NB8)          // 2210
#define KBLOCKS 256
#define PTS_PER_BLOCK (N_PTS / KBLOCKS)   // 4096
#define CAP 2048                 // counting-sort chunk (R9: was 4096; 15KB LDS
                                 // -> 8 blocks/CU = 32 waves/CU vs 20 before)

// K1: per-block LDS histogram over all 2210 buckets -> u16 matrix row.
__global__ __launch_bounds__(1024) void count_kernel(const int* __restrict__ inv1,
                                                     const int* __restrict__ inv8,
                                                     unsigned short* __restrict__ mat)
{
    __shared__ int hist[NBT];
    for (int k = threadIdx.x; k < NBT; k += 1024) hist[k] = 0;
    __syncthreads();
    int base_i = blockIdx.x * PTS_PER_BLOCK;
    for (int t = threadIdx.x; t < PTS_PER_BLOCK; t += 1024) {
        int i = base_i + t;
        atomicAdd(&hist[inv1[i] >> 8], 1);
        atomicAdd(&hist[NB1 + (inv8[i] >> 8)], 1);
    }
    __syncthreads();
    unsigned short* row = mat + (size_t)blockIdx.x * NBT;
    for (int k = threadIdx.x; k < NBT; k += 1024) row[k] = (unsigned short)hist[k];
}

// S1: per-bucket (column) exclusive scan over the 256 blocks, in place.
__global__ __launch_bounds__(256) void colscan_kernel(unsigned short* __restrict__ mat,
                                                      int* __restrict__ total)
{
    int wave = (int)((blockIdx.x * 256 + threadIdx.x) >> 6);
    int lane = threadIdx.x & 63;
    if (wave >= NBT) return;
    int carry = 0;
    for (int c = 0; c < KBLOCKS; c += 64) {
        int b = c + lane;
        int v = (int)mat[(size_t)b * NBT + wave];
        int s = v;
        #pragma unroll
        for (int d = 1; d < 64; d <<= 1) {
            int u = __shfl_up(s, d, 64);
            if (lane >= d) s += u;
        }
        mat[(size_t)b * NBT + wave] = (unsigned short)(s - v + carry);
        carry += __shfl(s, 63, 64);
    }
    if (lane == 0) total[wave] = carry;
}

// S2: exclusive scan of bucket totals -> base (separate per scale).
__global__ __launch_bounds__(64) void basescan_kernel(const int* __restrict__ total,
                                                      int* __restrict__ base)
{
    int lane = threadIdx.x;
    int carry = 0;
    for (int c = 0; c < NB1; c += 64) {
        int k = c + lane;
        int v = (k < NB1) ? total[k] : 0;
        int s = v;
        #pragma unroll
        for (int d = 1; d < 64; d <<= 1) {
            int u = __shfl_up(s, d, 64);
            if (lane >= d) s += u;
        }
        if (k < NB1) base[k] = s - v + carry;
        carry += __shfl(s, 63, 64);
    }
    carry = 0;
    for (int c = 0; c < NB8; c += 64) {
        int k = c + lane;
        int v = total[NB1 + k];
        int s = v;
        #pragma unroll
        for (int d = 1; d < 64; d <<= 1) {
            int u = __shfl_up(s, d, 64);
            if (lane >= d) s += u;
        }
        base[NB1 + k] = s - v + carry;
        carry += __shfl(s, 63, 64);
    }
}

// K2: place each point id (packed with 8-bit in-bucket bin) into sorted arrays.
__global__ __launch_bounds__(1024) void scatter_kernel(const int* __restrict__ inv1,
                                                       const int* __restrict__ inv8,
                                                       const unsigned short* __restrict__ mat,
                                                       const int* __restrict__ base,
                                                       int* __restrict__ sorted1,
                                                       int* __restrict__ sorted8)
{
    __shared__ int off[NBT];
    __shared__ int cnt[NBT];
    const unsigned short* row = mat + (size_t)blockIdx.x * NBT;
    for (int k = threadIdx.x; k < NBT; k += 1024) {
        off[k] = base[k] + (int)row[k];
        cnt[k] = 0;
    }
    __syncthreads();
    int base_i = blockIdx.x * PTS_PER_BLOCK;
    for (int t = threadIdx.x; t < PTS_PER_BLOCK; t += 1024) {
        int i = base_i + t;
        int v1 = inv1[i];
        int k1 = v1 >> 8;
        int r1 = atomicAdd(&cnt[k1], 1);
        sorted1[off[k1] + r1] = i | ((v1 & 255) << 20);
        int v8 = inv8[i];
        int k8 = NB1 + (v8 >> 8);
        int r8 = atomicAdd(&cnt[k8], 1);
        sorted8[off[k8] + r8] = i | ((v8 & 255) << 20);
    }
}

// K3: accumulation without per-channel LDS atomics (R8 structure, R9 tuning).
// Per bucket: in-LDS counting sort of row indices by bin (2 LDS atomics/row),
// then thread v register-accumulates its voxel's contiguous row list with
// plain f32 gathers (no atomics, latency-bound random line fetch), divides,
// writes output exactly once. CAP=2048 keeps LDS ~15KB -> 32 waves/CU.
__global__ __launch_bounds__(256) void accum_voxel_kernel(const float* __restrict__ points,
                                                          const float* __restrict__ labels,
                                                          const int* __restrict__ sorted1,
                                                          const int* __restrict__ sorted8,
                                                          const int* __restrict__ base,
                                                          const int* __restrict__ total,
                                                          float* __restrict__ feat_out,
                                                          float* __restrict__ lbl_out)
{
    __shared__ unsigned stage[CAP];        // sorted words of current chunk (8KB)
    __shared__ unsigned short perm[CAP];   // bin-sorted row order (4KB)
    __shared__ int hist[256];
    __shared__ int starts[256];
    __shared__ int cursor[256];
    __shared__ int wsum[4];

    const int tid  = threadIdx.x;
    const int lane = tid & 63;
    const int wid  = tid >> 6;

    if (blockIdx.x < NB8) {
        // ---------------- labels bucket ----------------
        int b = blockIdx.x;
        int start = base[NB1 + b];
        int num   = total[NB1 + b];
        float acc[C_LB];
        #pragma unroll
        for (int c = 0; c < C_LB; ++c) acc[c] = 0.0f;
        int mycnt = 0;

        for (int cbase = 0; cbase < num; cbase += CAP) {
            int csize = min(CAP, num - cbase);
            __syncthreads();                       // protect stage/perm reuse
            for (int t = tid; t < csize; t += 256)
                stage[t] = (unsigned)sorted8[start + cbase + t];
            hist[tid] = 0;
            __syncthreads();
            for (int t = tid; t < csize; t += 256)
                atomicAdd(&hist[stage[t] >> 20], 1);
            __syncthreads();
            // exclusive scan of hist (4-wave shfl scan + cross-wave offsets)
            int x = hist[tid];
            int s = x;
            #pragma unroll
            for (int d = 1; d < 64; d <<= 1) {
                int u = __shfl_up(s, d, 64);
                if (lane >= d) s += u;
            }
            if (lane == 63) wsum[wid] = s;
            __syncthreads();
            int off = 0;
            #pragma unroll
            for (int w = 0; w < 4; ++w) if (w < wid) off += wsum[w];
            starts[tid] = off + s - x;
            cursor[tid] = 0;
            __syncthreads();
            // rank: place row index into per-bin contiguous region
            for (int t = tid; t < csize; t += 256) {
                int bin = (int)(stage[t] >> 20);
                int r = atomicAdd(&cursor[bin], 1);
                perm[starts[bin] + r] = (unsigned short)t;
            }
            __syncthreads();
            // gather: thread tid owns voxel (b*256 + tid)
            int n  = hist[tid];
            int s0 = starts[tid];
            for (int j = 0; j < n; ++j) {
                int t = (int)perm[s0 + j];
                unsigned idx = stage[t] & 0xFFFFFu;
                const float4* __restrict__ r4 =
                    reinterpret_cast<const float4*>(labels) + (size_t)idx * 5;
                float4 v0 = r4[0], v1 = r4[1], v2 = r4[2], v3 = r4[3], v4 = r4[4];
                acc[0]  += v0.x; acc[1]  += v0.y; acc[2]  += v0.z; acc[3]  += v0.w;
                acc[4]  += v1.x; acc[5]  += v1.y; acc[6]  += v1.z; acc[7]  += v1.w;
                acc[8]  += v2.x; acc[9]  += v2.y; acc[10] += v2.z; acc[11] += v2.w;
                acc[12] += v3.x; acc[13] += v3.y; acc[14] += v3.z; acc[15] += v3.w;
                acc[16] += v4.x; acc[17] += v4.y; acc[18] += v4.z; acc[19] += v4.w;
            }
            mycnt += n;
        }
        float inv = 1.0f / (float)(mycnt > 0 ? mycnt : 1);
        // lbl_out base offset = V1*C_PT floats (16B-aligned); 80B rows.
        float4* orow = reinterpret_cast<float4*>(lbl_out + ((size_t)b * 256 + tid) * C_LB);
        orow[0] = make_float4(acc[0] * inv,  acc[1] * inv,  acc[2] * inv,  acc[3] * inv);
        orow[1] = make_float4(acc[4] * inv,  acc[5] * inv,  acc[6] * inv,  acc[7] * inv);
        orow[2] = make_float4(acc[8] * inv,  acc[9] * inv,  acc[10] * inv, acc[11] * inv);
        orow[3] = make_float4(acc[12] * inv, acc[13] * inv, acc[14] * inv, acc[15] * inv);
        orow[4] = make_float4(acc[16] * inv, acc[17] * inv, acc[18] * inv, acc[19] * inv);
    } else {
        // ---------------- points bucket ----------------
        int b = blockIdx.x - NB8;
        int start = base[b];
        int num   = total[b];
        float acc[C_PT];
        #pragma unroll
        for (int c = 0; c < C_PT; ++c) acc[c] = 0.0f;
        int mycnt = 0;

        for (int cbase = 0; cbase < num; cbase += CAP) {
            int csize = min(CAP, num - cbase);
            __syncthreads();
            for (int t = tid; t < csize; t += 256)
                stage[t] = (unsigned)sorted1[start + cbase + t];
            hist[tid] = 0;
            __syncthreads();
            for (int t = tid; t < csize; t += 256)
                atomicAdd(&hist[stage[t] >> 20], 1);
            __syncthreads();
            int x = hist[tid];
            int s = x;
            #pragma unroll
            for (int d = 1; d < 64; d <<= 1) {
                int u = __shfl_up(s, d, 64);
                if (lane >= d) s += u;
            }
            if (lane == 63) wsum[wid] = s;
            __syncthreads();
            int off = 0;
            #pragma unroll
            for (int w = 0; w < 4; ++w) if (w < wid) off += wsum[w];
            starts[tid] = off + s - x;
            cursor[tid] = 0;
            __syncthreads();
            for (int t = tid; t < csize; t += 256) {
                int bin = (int)(stage[t] >> 20);
                int r = atomicAdd(&cursor[bin], 1);
                perm[starts[bin] + r] = (unsigned short)t;
            }
            __syncthreads();
            int n  = hist[tid];
            int s0 = starts[tid];
            for (int j = 0; j < n; ++j) {
                int t = (int)perm[s0 + j];
                unsigned idx = stage[t] & 0xFFFFFu;
                const float* __restrict__ r = points + (size_t)idx * C_PT;
                float p0 = r[0], p1 = r[1], p2 = r[2], p3 = r[3], p4 = r[4];
                float p5 = r[5], p6 = r[6], p7 = r[7], p8 = r[8];
                acc[0] += p0; acc[1] += p1; acc[2] += p2; acc[3] += p3;
                acc[4] += p4; acc[5] += p5; acc[6] += p6; acc[7] += p7;
                acc[8] += p8;
            }
            mycnt += n;
        }
        int v = b * 256 + tid;
        if (v < V1) {
            float inv = 1.0f / (float)(mycnt > 0 ? mycnt : 1);
            float* __restrict__ orow = feat_out + (size_t)v * C_PT;
            #pragma unroll
            for (int c = 0; c < C_PT; ++c) orow[c] = acc[c] * inv;
        }
    }
}

// ---------------- Fallback: R0 atomic scatter (ws tiny) --------------------
__global__ void voxel_scatter_add_kernel(const float* __restrict__ points,
                                         const int* __restrict__ inv1,
                                         const float* __restrict__ labels,
                                         const int* __restrict__ inv8,
                                         float* feat_sum, float* lbl_sum,
                                         float* cnt1, float* cnt8)
{
    int i = blockIdx.x * blockDim.x + threadIdx.x;
    if (i >= N_PTS) return;
    int v1 = inv1[i];
    int v8 = inv8[i];
    const float* p = points + (size_t)i * C_PT;
    float* f = feat_sum + (size_t)v1 * C_PT;
#pragma unroll
    for (int c = 0; c < C_PT; ++c) atomicAdd(&f[c], p[c]);
    atomicAdd(&cnt1[v1], 1.0f);
    const float* l = labels + (size_t)i * C_LB;
    float* o = lbl_sum + (size_t)v8 * C_LB;
#pragma unroll
    for (int c = 0; c < C_LB; ++c) atomicAdd(&o[c], l[c]);
    atomicAdd(&cnt8[v8], 1.0f);
}

__global__ void voxel_divide_kernel(float* out, const float* cnt1, const float* cnt8)
{
    const int totaln = V1 * C_PT + V8 * C_LB;
    for (int i = blockIdx.x * blockDim.x + threadIdx.x; i < totaln;
         i += gridDim.x * blockDim.x) {
        float c = (i < V1 * C_PT) ? cnt1[i / C_PT] : cnt8[(i - V1 * C_PT) / C_LB];
        out[i] /= fmaxf(c, 1.0f);
    }
}

extern "C" void kernel_launch(void* const* d_in, const int* in_sizes, int n_in,
                              void* d_out, int out_size, void* d_ws, size_t ws_size,
                              hipStream_t stream) {
    const float* points = (const float*)d_in[0];
    const int*   inv1   = (const int*)d_in[1];
    const float* labels = (const float*)d_in[2];
    const int*   inv8   = (const int*)d_in[3];

    float* out      = (float*)d_out;
    float* feat_out = out;                       // [V1, C_PT]
    float* lbl_out  = out + (size_t)V1 * C_PT;   // [V8, C_LB]

    // ws layout (EXACT R2, proven): sorted1[N] | sorted8[N] | total[NBT] |
    //                               base[NBT] | mat u16[256][NBT]   (~9.45 MB)
    const size_t need = ((size_t)2 * N_PTS + 2 * NBT) * sizeof(int)
                      + (size_t)KBLOCKS * NBT * sizeof(unsigned short);
    if (ws_size >= need) {
        int* sorted1 = (int*)d_ws;
        int* sorted8 = sorted1 + N_PTS;
        int* total   = sorted8 + N_PTS;
        int* basep   = total + NBT;
        unsigned short* mat = (unsigned short*)(basep + NBT);

        count_kernel<<<KBLOCKS, 1024, 0, stream>>>(inv1, inv8, mat);
        colscan_kernel<<<(NBT + 3) / 4, 256, 0, stream>>>(mat, total);
        basescan_kernel<<<1, 64, 0, stream>>>(total, basep);
        scatter_kernel<<<KBLOCKS, 1024, 0, stream>>>(inv1, inv8, mat, basep,
                                                     sorted1, sorted8);
        accum_voxel_kernel<<<NB8 + NB1, 256, 0, stream>>>(points, labels, sorted1,
                                                          sorted8, basep, total,
                                                          feat_out, lbl_out);
    } else {
        // Fallback: naive atomic scatter (correct, slower).
        float* cnt1 = (float*)d_ws;
        float* cnt8 = cnt1 + V1;
        hipMemsetAsync(d_out, 0, (size_t)out_size * sizeof(float), stream);
        hipMemsetAsync(d_ws, 0, ((size_t)V1 + V8) * sizeof(float), stream);
        const int block = 256;
        voxel_scatter_add_kernel<<<(N_PTS + block - 1) / block, block, 0, stream>>>(
            points, inv1, labels, inv8, feat_out, lbl_out, cnt1, cnt8);
        voxel_divide_kernel<<<2048, block, 0, stream>>>(out, cnt1, cnt8);
    }
}